// Round 7
// baseline (1220.438 us; speedup 1.0000x reference)
//
#include <hip/hip_runtime.h>
#include <hip/hip_bf16.h>
#include <initializer_list>

typedef _Float16 half8 __attribute__((ext_vector_type(8)));
typedef float floatx4 __attribute__((ext_vector_type(4)));

#define MFMA16(a, b, c) __builtin_amdgcn_mfma_f32_16x16x32_f16((a), (b), (c), 0, 0, 0)

// async global->LDS, 16B per lane; LDS dest = wave-uniform base + lane*16
__device__ __forceinline__ void gload16(const void* g, void* l) {
    __builtin_amdgcn_global_load_lds((const __attribute__((address_space(1))) unsigned int*)g,
                                     (__attribute__((address_space(3))) unsigned int*)l,
                                     16, 0, 0);
}

// ---------------------------------------------------------------- LayerNorm
__global__ __launch_bounds__(256) void ln_kernel(const float* __restrict__ x,
                                                 const float* __restrict__ gamma,
                                                 const float* __restrict__ beta,
                                                 _Float16* __restrict__ xn) {
    int row = blockIdx.x;
    int tid = threadIdx.x;
    float2 v = ((const float2*)(x + (size_t)row * 512))[tid];

    __shared__ float red[4];
    __shared__ float mv[2];

    float s = v.x + v.y;
#pragma unroll
    for (int o = 32; o > 0; o >>= 1) s += __shfl_down(s, o);
    if ((tid & 63) == 0) red[tid >> 6] = s;
    __syncthreads();
    if (tid == 0) mv[0] = (red[0] + red[1] + red[2] + red[3]) * (1.f / 512.f);
    __syncthreads();
    float mean = mv[0];

    float dx = v.x - mean, dy = v.y - mean;
    float sq = dx * dx + dy * dy;
#pragma unroll
    for (int o = 32; o > 0; o >>= 1) sq += __shfl_xor(sq, o);
    __syncthreads();
    if ((tid & 63) == 0) red[tid >> 6] = sq;
    __syncthreads();
    if (tid == 0) mv[1] = rsqrtf((red[0] + red[1] + red[2] + red[3]) * (1.f / 512.f) + 1e-5f);
    __syncthreads();
    float rstd = mv[1];

    float g0 = gamma[tid * 2], g1 = gamma[tid * 2 + 1];
    float b0 = beta[tid * 2], b1 = beta[tid * 2 + 1];
    union { _Float16 h[2]; unsigned int u; } pk;
    pk.h[0] = (_Float16)(dx * rstd * g0 + b0);
    pk.h[1] = (_Float16)(dy * rstd * g1 + b1);
    ((unsigned int*)(xn + (size_t)row * 512))[tid] = pk.u;
}

// ------------------------------------------------- tiled transpose + cast fp32->fp16
__global__ __launch_bounds__(256) void transpose_cast(const float* __restrict__ in,
                                                      _Float16* __restrict__ out,
                                                      int R, int C) {
    __shared__ float t[32][33];
    int c0 = blockIdx.x * 32, r0 = blockIdx.y * 32;
    int tx = threadIdx.x & 31, ty = threadIdx.x >> 5;
#pragma unroll
    for (int j = 0; j < 4; ++j)
        t[ty + j * 8][tx] = in[(size_t)(r0 + ty + j * 8) * C + c0 + tx];
    __syncthreads();
#pragma unroll
    for (int j = 0; j < 4; ++j)
        out[(size_t)(c0 + ty + j * 8) * R + r0 + tx] = (_Float16)t[tx][ty + j * 8];
}

// ---------------------------------------------------------------- GEMM (B^T)
// OUTMODE 2's V writer stores vt in the PV-FRAGMENT-PERMUTED key order:
// within each 32-token tile, token kk = t*16 + q8*4 + r  ->  col q8*8 + t*4 + r.
// This lets the attention kernel DMA V linearly (global_load_lds) and feed the
// PV MFMA A-fragment without any repacking.
template <int OUTMODE>
__global__ __launch_bounds__(256) void gemm_bt(const _Float16* __restrict__ A,
                                               const _Float16* __restrict__ Bt,
                                               const float* __restrict__ bias,
                                               void* __restrict__ Cout,
                                               _Float16* __restrict__ Vt,
                                               int M, int N, int K) {
    __shared__ __align__(16) _Float16 Asb[128 * 32];
    __shared__ __align__(16) _Float16 Bsb[128 * 32];

    int m0 = blockIdx.x * 128;
    int n0 = blockIdx.y * 128;
    int tid = threadIdx.x;
    int w = tid >> 6, lane = tid & 63, lrow = lane & 15, quad = lane >> 4;
    int wm = (w >> 1) * 64, wn = (w & 1) * 64;

    int hh = 0, part = 0;
    bool sw = false;
    if (OUTMODE == 2) {
        hh = blockIdx.y / 3;
        part = blockIdx.y - hh * 3;
        sw = (part != 0);
    }

    int srow = lane >> 2;
    int scb = (lane & 3) ^ ((lane >> 3) & 3);
    const _Float16* Abase = A + (size_t)(m0 + w * 16 + srow) * K + scb * 8;
    const _Float16* Bbase = Bt + (size_t)(n0 + w * 16 + srow) * K + scb * 8;
    char* AldsB = (char*)Asb + w * 1024;
    char* BldsB = (char*)Bsb + w * 1024;
    const size_t rowskip = (size_t)64 * K;

    int swz = (lrow >> 1) & 3;

    floatx4 acc[4][4];
#pragma unroll
    for (int i = 0; i < 4; ++i)
#pragma unroll
        for (int j = 0; j < 4; ++j) acc[i][j] = (floatx4){0.f, 0.f, 0.f, 0.f};

    for (int k0 = 0; k0 < K; k0 += 32) {
        __syncthreads();
        gload16(Abase + k0, AldsB);
        gload16(Abase + rowskip + k0, AldsB + 4096);
        gload16(Bbase + k0, BldsB);
        gload16(Bbase + rowskip + k0, BldsB + 4096);
        __syncthreads();

        half8 af[4], bf[4];
#pragma unroll
        for (int i = 0; i < 4; ++i) {
            int r = wm + i * 16 + lrow;
            af[i] = *(const half8*)&Asb[r * 32 + (quad ^ swz) * 8];
        }
#pragma unroll
        for (int j = 0; j < 4; ++j) {
            int r = wn + j * 16 + lrow;
            bf[j] = *(const half8*)&Bsb[r * 32 + (quad ^ swz) * 8];
        }
        if (OUTMODE == 2 && sw) {
#pragma unroll
            for (int i = 0; i < 4; ++i)
#pragma unroll
                for (int j = 0; j < 4; ++j)
                    acc[i][j] = MFMA16(bf[j], af[i], acc[i][j]);
        } else {
#pragma unroll
            for (int i = 0; i < 4; ++i)
#pragma unroll
                for (int j = 0; j < 4; ++j)
                    acc[i][j] = MFMA16(af[i], bf[j], acc[i][j]);
        }
    }

    if (OUTMODE == 2 && sw) {
        // transposed fragment: lane lrow <-> token, quad*4+r <-> d
        // token tok0 + i*16 + lrow stored PERMUTED: tile (i>>1), col (lrow>>2)*8 + (i&1)*4 + (lrow&3)
        int b_rel = m0 >> 10;
        int tok0 = (m0 & 1023) + wm;  // 64-aligned
        _Float16* vbase = Vt + (((size_t)b_rel * 8 + hh) * 256 + (part - 1) * 128) * 1024;
        int poff0 = ((lrow >> 2) << 3) + (lrow & 3);
#pragma unroll
        for (int j = 0; j < 4; ++j)
#pragma unroll
            for (int r = 0; r < 4; ++r) {
                int d = wn + j * 16 + quad * 4 + r;
                float bv = bias[n0 + d];
                _Float16* vrow = vbase + (size_t)d * 1024 + tok0;
#pragma unroll
                for (int i = 0; i < 4; ++i)
                    vrow[(i >> 1) * 32 + ((i & 1) << 2) + poff0] = (_Float16)(acc[i][j][r] + bv);
            }
        return;
    }

#pragma unroll
    for (int i = 0; i < 4; ++i)
#pragma unroll
        for (int j = 0; j < 4; ++j) {
            int colg = n0 + wn + j * 16 + lrow;
            int coll = wn + j * 16 + lrow;
            float bv = bias[colg];
#pragma unroll
            for (int r = 0; r < 4; ++r) {
                int rowg = m0 + wm + i * 16 + quad * 4 + r;
                float v = acc[i][j][r] + bv;
                if (OUTMODE == 1) {
                    ((float*)Cout)[(size_t)rowg * N + colg] = v;
                } else {
                    ((_Float16*)Cout)[(size_t)rowg * 1024 + hh * 128 + coll] = (_Float16)v;
                }
            }
        }
}

// ---------------------------------------------------------------- attention
// 2 q-frags/wave (32 q-rows), 128 q/block, double-buffered K/V staged by
// global_load_lds (zero staging VGPRs -> 3 waves/SIMD). K stored with
// source-pre-swizzled col-blocks (cb ^ (row&7)); V arrives from vt already in
// PV-fragment key order (permuted at the producer), staged linearly.
__global__ __launch_bounds__(256, 3) void attn_kernel(const _Float16* __restrict__ qk,
                                                      const _Float16* __restrict__ vt,
                                                      const float* __restrict__ biases,
                                                      _Float16* __restrict__ out) {
    int h  = blockIdx.x;   // 0..7 -> XCD = h
    int qt = blockIdx.y;   // 0..7, 128 q-rows each
    int b  = blockIdx.z;

    int tid = threadIdx.x;
    int w = tid >> 6, lane = tid & 63, lrow = lane & 15, quad = lane >> 4;

    __shared__ float bias_lds[1024];
    __shared__ __align__(16) _Float16 K_lds[2][32 * 64];  // [key][kd], col-blocks XOR'd by key&7
    __shared__ __align__(16) _Float16 V_s[2][256 * 32];   // [d][k-slot], PV-permuted key order

    for (int i = tid; i < 1024; i += 256) bias_lds[i] = biases[h * 1024 + i];

    // ---- Q fragments: frag f covers q-rows qt*128 + w*32 + f*16 + (0..15) ----
    int q0 = qt * 128 + w * 32 + lrow;
    const _Float16* qb = qk + ((size_t)(b * 1024 + q0)) * 1024 + h * 128;
    half8 aq[2][2];
    aq[0][0] = *(const half8*)(qb + quad * 8);
    aq[0][1] = *(const half8*)(qb + 32 + quad * 8);
    aq[1][0] = *(const half8*)(qb + 16 * 1024 + quad * 8);
    aq[1][1] = *(const half8*)(qb + 16 * 1024 + 32 + quad * 8);

    // ---- staging sources (per-lane global addresses; LDS dest is linear DMA) ----
    int kswz = (lane & 7) ^ ((lane >> 3) & 7);
    const _Float16* ksrc_g = qk + ((size_t)(b * 1024 + w * 8 + (lane >> 3))) * 1024 + h * 128 + 64 + kswz * 8;
    const _Float16* vsrc_g = vt + ((size_t)((b * 8 + h) * 256 + w * 64 + (lane >> 2))) * 1024 + (lane & 3) * 8;

    // ---- K read offsets (halves), loop-invariant: stored cb = (data cb) ^ (row&7)
    int koff0 = lrow * 64 + ((quad) ^ (lrow & 7)) * 8;
    int koff1 = lrow * 64 + ((4 + quad) ^ (lrow & 7)) * 8;

    int qr = qt * 4 + w;

    float m_[2] = {-1e30f, -1e30f}, l_[2] = {0.f, 0.f};
    floatx4 od[2][16];
#pragma unroll
    for (int f = 0; f < 2; ++f)
#pragma unroll
        for (int dt = 0; dt < 16; ++dt) od[f][dt] = (floatx4){0.f, 0.f, 0.f, 0.f};

#define STAGE(t)                                                                  \
    do {                                                                          \
        int bb_ = (t) & 1;                                                        \
        gload16(ksrc_g + (size_t)(t) * 32 * 1024, &K_lds[bb_][w * 8 * 64]);       \
        _Pragma("unroll") for (int it = 0; it < 4; ++it)                          \
            gload16(vsrc_g + (size_t)it * 16 * 1024 + (t) * 32,                   \
                    &V_s[bb_][(w * 64 + it * 16) * 32]);                          \
    } while (0)

    STAGE(0);
    __syncthreads();  // drains vmcnt -> tile 0 resident

    for (int kt = 0; kt < 32; ++kt) {
        int bufc = kt & 1;
        const _Float16* Kc = K_lds[bufc];
        const _Float16* Vc = V_s[bufc];

        // issue next tile's DMA into the other buffer (drained by end-of-iter barrier)
        if (kt < 31) STAGE(kt + 1);

        // ---- QK^T (swapped): sc[f][t][r] = S[q = lrow + f*16][key = t*16 + quad*4 + r]
        floatx4 sc[2][2];
#pragma unroll
        for (int f = 0; f < 2; ++f)
#pragma unroll
            for (int t = 0; t < 2; ++t) sc[f][t] = (floatx4){0.f, 0.f, 0.f, 0.f};
        {
            half8 ka = *(const half8*)&Kc[koff0];
            half8 kb = *(const half8*)&Kc[koff1];
            sc[0][0] = MFMA16(ka, aq[0][0], sc[0][0]);
            sc[0][0] = MFMA16(kb, aq[0][1], sc[0][0]);
            sc[1][0] = MFMA16(ka, aq[1][0], sc[1][0]);
            sc[1][0] = MFMA16(kb, aq[1][1], sc[1][0]);
            ka = *(const half8*)&Kc[16 * 64 + koff0];
            kb = *(const half8*)&Kc[16 * 64 + koff1];
            sc[0][1] = MFMA16(ka, aq[0][0], sc[0][1]);
            sc[0][1] = MFMA16(kb, aq[0][1], sc[0][1]);
            sc[1][1] = MFMA16(ka, aq[1][0], sc[1][1]);
            sc[1][1] = MFMA16(kb, aq[1][1], sc[1][1]);
        }

        int rowoff = abs(qr - kt) << 5;
        union H8 { _Float16 hh[8]; half8 v; } pa[2];

#pragma unroll
        for (int f = 0; f < 2; ++f) {
            int qcf = lrow + f * 16;
            float s_[8];
#pragma unroll
            for (int t = 0; t < 2; ++t)
#pragma unroll
                for (int r = 0; r < 4; ++r) {
                    int kc = t * 16 + quad * 4 + r;
                    s_[t * 4 + r] = sc[f][t][r] * 0.125f + bias_lds[rowoff + abs(qcf - kc)];
                }

            float pmax = fmaxf(fmaxf(fmaxf(s_[0], s_[1]), fmaxf(s_[2], s_[3])),
                               fmaxf(fmaxf(s_[4], s_[5]), fmaxf(s_[6], s_[7])));
            pmax = fmaxf(pmax, __shfl_xor(pmax, 16));
            pmax = fmaxf(pmax, __shfl_xor(pmax, 32));

            if (!__all(pmax - m_[f] <= 8.f)) {
                float mnew = fmaxf(m_[f], pmax);
                float alpha = __expf(m_[f] - mnew);
                m_[f] = mnew;
                l_[f] *= alpha;
                float a4[4];
#pragma unroll
                for (int r = 0; r < 4; ++r) a4[r] = __shfl(alpha, quad * 4 + r, 16);
#pragma unroll
                for (int dt = 0; dt < 16; ++dt)
#pragma unroll
                    for (int r = 0; r < 4; ++r) od[f][dt][r] *= a4[r];
            }

            float rs = 0.f;
#pragma unroll
            for (int i = 0; i < 8; ++i) {
                float p = __expf(s_[i] - m_[f]);
                pa[f].hh[i] = (_Float16)p;
                rs += p;
            }
            rs += __shfl_xor(rs, 16);
            rs += __shfl_xor(rs, 32);
            l_[f] += rs;
        }

        // ---- PV: one bv read feeds both fragments ----
#pragma unroll
        for (int dt = 0; dt < 16; ++dt) {
            half8 bv = *(const half8*)&Vc[(dt * 16 + lrow) * 32 + quad * 8];
            od[0][dt] = MFMA16(pa[0].v, bv, od[0][dt]);
            od[1][dt] = MFMA16(pa[1].v, bv, od[1][dt]);
        }
        __syncthreads();  // waves done with bufc; DMA for kt+1 drained
    }
#undef STAGE

#pragma unroll
    for (int f = 0; f < 2; ++f)
#pragma unroll
        for (int r = 0; r < 4; ++r) {
            float lq = __shfl(l_[f], quad * 4 + r, 16);
            float inv = 1.f / lq;
            int qg = qt * 128 + w * 32 + f * 16 + quad * 4 + r;
            _Float16* orow = out + ((size_t)(b * 1024 + qg)) * 2048 + h * 256;
#pragma unroll
            for (int dt = 0; dt < 16; ++dt)
                orow[dt * 16 + lrow] = (_Float16)(od[f][dt][r] * inv);
        }
}

// ---------------------------------------------------------------- launch
extern "C" void kernel_launch(void* const* d_in, const int* in_sizes, int n_in,
                              void* d_out, int out_size, void* d_ws, size_t ws_size,
                              hipStream_t stream) {
    const float* x      = (const float*)d_in[0];
    const float* gamma  = (const float*)d_in[1];
    const float* beta   = (const float*)d_in[2];
    const float* qkv_w  = (const float*)d_in[3];
    const float* qkv_b  = (const float*)d_in[4];
    const float* proj_w = (const float*)d_in[5];
    const float* proj_b = (const float*)d_in[6];
    const float* biases = (const float*)d_in[7];

    float* out = (float*)d_out;

    _Float16* ws      = (_Float16*)d_ws;
    _Float16* qkv_wt  = ws;                                   //  512*3072
    _Float16* proj_wt = qkv_wt + (size_t)512 * 3072;          // 2048*512
    _Float16* xn      = proj_wt + (size_t)2048 * 512;         // 32768*512
    _Float16* chunk0  = xn + (size_t)32768 * 512;

    const size_t FIXED_HALVES = (size_t)512 * 3072 + (size_t)2048 * 512 + (size_t)32768 * 512;
    int CB = 0;
    for (int cb : {16, 8, 4, 2, 1}) {
        size_t halves = FIXED_HALVES + (size_t)cb * 1024 * (1024 + 2048 + 2048);
        if (halves * sizeof(_Float16) <= ws_size) { CB = cb; break; }
    }
    if (CB == 0) return;
    _Float16* qk_c  = chunk0;                                 // CB*1024*1024
    _Float16* vt_c  = qk_c + (size_t)CB * 1024 * 1024;        // CB*1024*2048
    _Float16* att_c = vt_c + (size_t)CB * 1024 * 2048;        // CB*1024*2048

    transpose_cast<<<dim3(3072 / 32, 512 / 32), 256, 0, stream>>>(qkv_w, qkv_wt, 512, 3072);
    transpose_cast<<<dim3(512 / 32, 2048 / 32), 256, 0, stream>>>(proj_w, proj_wt, 2048, 512);
    ln_kernel<<<32768, 256, 0, stream>>>(x, gamma, beta, xn);

    const int MC = CB * 1024;
    for (int c = 0; c < 32 / CB; ++c) {
        const _Float16* xn_c = xn + (size_t)c * MC * 512;
        gemm_bt<2><<<dim3(MC / 128, 24), 256, 0, stream>>>(xn_c, qkv_wt, qkv_b,
                                                           (void*)qk_c, vt_c, MC, 3072, 512);
        attn_kernel<<<dim3(8, 8, CB), 256, 0, stream>>>(qk_c, vt_c, biases, att_c);
        float* out_c = out + (size_t)c * MC * 512;
        gemm_bt<1><<<dim3(MC / 128, 4), 256, 0, stream>>>(att_c, proj_wt, proj_b,
                                                          (void*)out_c, nullptr, MC, 512, 2048);
    }
}

// Round 8
// 906.646 us; speedup vs baseline: 1.3461x; 1.3461x over previous
//
#include <hip/hip_runtime.h>
#include <hip/hip_bf16.h>
#include <initializer_list>

typedef _Float16 half8 __attribute__((ext_vector_type(8)));
typedef float floatx4 __attribute__((ext_vector_type(4)));

#define MFMA16(a, b, c) __builtin_amdgcn_mfma_f32_16x16x32_f16((a), (b), (c), 0, 0, 0)

// async global->LDS, 16B per lane; LDS dest = wave-uniform base + lane*16
__device__ __forceinline__ void gload16(const void* g, void* l) {
    __builtin_amdgcn_global_load_lds((const __attribute__((address_space(1))) unsigned int*)g,
                                     (__attribute__((address_space(3))) unsigned int*)l,
                                     16, 0, 0);
}

// ---------------------------------------------------------------- LayerNorm
__global__ __launch_bounds__(256) void ln_kernel(const float* __restrict__ x,
                                                 const float* __restrict__ gamma,
                                                 const float* __restrict__ beta,
                                                 _Float16* __restrict__ xn) {
    int row = blockIdx.x;
    int tid = threadIdx.x;
    float2 v = ((const float2*)(x + (size_t)row * 512))[tid];

    __shared__ float red[4];
    __shared__ float mv[2];

    float s = v.x + v.y;
#pragma unroll
    for (int o = 32; o > 0; o >>= 1) s += __shfl_down(s, o);
    if ((tid & 63) == 0) red[tid >> 6] = s;
    __syncthreads();
    if (tid == 0) mv[0] = (red[0] + red[1] + red[2] + red[3]) * (1.f / 512.f);
    __syncthreads();
    float mean = mv[0];

    float dx = v.x - mean, dy = v.y - mean;
    float sq = dx * dx + dy * dy;
#pragma unroll
    for (int o = 32; o > 0; o >>= 1) sq += __shfl_xor(sq, o);
    __syncthreads();
    if ((tid & 63) == 0) red[tid >> 6] = sq;
    __syncthreads();
    if (tid == 0) mv[1] = rsqrtf((red[0] + red[1] + red[2] + red[3]) * (1.f / 512.f) + 1e-5f);
    __syncthreads();
    float rstd = mv[1];

    float g0 = gamma[tid * 2], g1 = gamma[tid * 2 + 1];
    float b0 = beta[tid * 2], b1 = beta[tid * 2 + 1];
    union { _Float16 h[2]; unsigned int u; } pk;
    pk.h[0] = (_Float16)(dx * rstd * g0 + b0);
    pk.h[1] = (_Float16)(dy * rstd * g1 + b1);
    ((unsigned int*)(xn + (size_t)row * 512))[tid] = pk.u;
}

// ------------------------------------------------- tiled transpose + cast fp32->fp16
__global__ __launch_bounds__(256) void transpose_cast(const float* __restrict__ in,
                                                      _Float16* __restrict__ out,
                                                      int R, int C) {
    __shared__ float t[32][33];
    int c0 = blockIdx.x * 32, r0 = blockIdx.y * 32;
    int tx = threadIdx.x & 31, ty = threadIdx.x >> 5;
#pragma unroll
    for (int j = 0; j < 4; ++j)
        t[ty + j * 8][tx] = in[(size_t)(r0 + ty + j * 8) * C + c0 + tx];
    __syncthreads();
#pragma unroll
    for (int j = 0; j < 4; ++j)
        out[(size_t)(c0 + ty + j * 8) * R + r0 + tx] = (_Float16)t[tx][ty + j * 8];
}

// ---------------------------------------------------------------- GEMM (B^T)
// OUTMODE 2's V writer stores vt in the PV-FRAGMENT-PERMUTED key order:
// within each 32-token tile, token kk = t*16 + q8*4 + r  ->  col q8*8 + t*4 + r.
// This lets the attention kernel DMA V linearly (global_load_lds) and feed the
// PV MFMA A-fragment without any repacking.
template <int OUTMODE>
__global__ __launch_bounds__(256) void gemm_bt(const _Float16* __restrict__ A,
                                               const _Float16* __restrict__ Bt,
                                               const float* __restrict__ bias,
                                               void* __restrict__ Cout,
                                               _Float16* __restrict__ Vt,
                                               int M, int N, int K) {
    __shared__ __align__(16) _Float16 Asb[128 * 32];
    __shared__ __align__(16) _Float16 Bsb[128 * 32];

    int m0 = blockIdx.x * 128;
    int n0 = blockIdx.y * 128;
    int tid = threadIdx.x;
    int w = tid >> 6, lane = tid & 63, lrow = lane & 15, quad = lane >> 4;
    int wm = (w >> 1) * 64, wn = (w & 1) * 64;

    int hh = 0, part = 0;
    bool sw = false;
    if (OUTMODE == 2) {
        hh = blockIdx.y / 3;
        part = blockIdx.y - hh * 3;
        sw = (part != 0);
    }

    int srow = lane >> 2;
    int scb = (lane & 3) ^ ((lane >> 3) & 3);
    const _Float16* Abase = A + (size_t)(m0 + w * 16 + srow) * K + scb * 8;
    const _Float16* Bbase = Bt + (size_t)(n0 + w * 16 + srow) * K + scb * 8;
    char* AldsB = (char*)Asb + w * 1024;
    char* BldsB = (char*)Bsb + w * 1024;
    const size_t rowskip = (size_t)64 * K;

    int swz = (lrow >> 1) & 3;

    floatx4 acc[4][4];
#pragma unroll
    for (int i = 0; i < 4; ++i)
#pragma unroll
        for (int j = 0; j < 4; ++j) acc[i][j] = (floatx4){0.f, 0.f, 0.f, 0.f};

    for (int k0 = 0; k0 < K; k0 += 32) {
        __syncthreads();
        gload16(Abase + k0, AldsB);
        gload16(Abase + rowskip + k0, AldsB + 4096);
        gload16(Bbase + k0, BldsB);
        gload16(Bbase + rowskip + k0, BldsB + 4096);
        __syncthreads();

        half8 af[4], bf[4];
#pragma unroll
        for (int i = 0; i < 4; ++i) {
            int r = wm + i * 16 + lrow;
            af[i] = *(const half8*)&Asb[r * 32 + (quad ^ swz) * 8];
        }
#pragma unroll
        for (int j = 0; j < 4; ++j) {
            int r = wn + j * 16 + lrow;
            bf[j] = *(const half8*)&Bsb[r * 32 + (quad ^ swz) * 8];
        }
        if (OUTMODE == 2 && sw) {
#pragma unroll
            for (int i = 0; i < 4; ++i)
#pragma unroll
                for (int j = 0; j < 4; ++j)
                    acc[i][j] = MFMA16(bf[j], af[i], acc[i][j]);
        } else {
#pragma unroll
            for (int i = 0; i < 4; ++i)
#pragma unroll
                for (int j = 0; j < 4; ++j)
                    acc[i][j] = MFMA16(af[i], bf[j], acc[i][j]);
        }
    }

    if (OUTMODE == 2 && sw) {
        // transposed fragment: lane lrow <-> token, quad*4+r <-> d
        // token tok0 + i*16 + lrow stored PERMUTED: tile (i>>1), col (lrow>>2)*8 + (i&1)*4 + (lrow&3)
        int b_rel = m0 >> 10;
        int tok0 = (m0 & 1023) + wm;  // 64-aligned
        _Float16* vbase = Vt + (((size_t)b_rel * 8 + hh) * 256 + (part - 1) * 128) * 1024;
        int poff0 = ((lrow >> 2) << 3) + (lrow & 3);
#pragma unroll
        for (int j = 0; j < 4; ++j)
#pragma unroll
            for (int r = 0; r < 4; ++r) {
                int d = wn + j * 16 + quad * 4 + r;
                float bv = bias[n0 + d];
                _Float16* vrow = vbase + (size_t)d * 1024 + tok0;
#pragma unroll
                for (int i = 0; i < 4; ++i)
                    vrow[(i >> 1) * 32 + ((i & 1) << 2) + poff0] = (_Float16)(acc[i][j][r] + bv);
            }
        return;
    }

#pragma unroll
    for (int i = 0; i < 4; ++i)
#pragma unroll
        for (int j = 0; j < 4; ++j) {
            int colg = n0 + wn + j * 16 + lrow;
            int coll = wn + j * 16 + lrow;
            float bv = bias[colg];
#pragma unroll
            for (int r = 0; r < 4; ++r) {
                int rowg = m0 + wm + i * 16 + quad * 4 + r;
                float v = acc[i][j][r] + bv;
                if (OUTMODE == 1) {
                    ((float*)Cout)[(size_t)rowg * N + colg] = v;
                } else {
                    ((_Float16*)Cout)[(size_t)rowg * 1024 + hh * 128 + coll] = (_Float16)v;
                }
            }
        }
}

// ---------------------------------------------------------------- attention
// 2 q-frags/wave (32 q-rows), 128 q/block, double-buffered K/V staged by
// global_load_lds (zero staging VGPRs). K stored with source-pre-swizzled
// col-blocks (cb ^ (row&7)); V arrives from vt already in PV-fragment key
// order (permuted at the producer), staged linearly.
// NOTE: no min-waves clause — round 7's (256,3) forced VGPR to 84 and the
// od[2][16] accumulators spilled to scratch (FETCH 49->244 MB, WRITE 65->306 MB).
__global__ __launch_bounds__(256) void attn_kernel(const _Float16* __restrict__ qk,
                                                   const _Float16* __restrict__ vt,
                                                   const float* __restrict__ biases,
                                                   _Float16* __restrict__ out) {
    int h  = blockIdx.x;   // 0..7 -> XCD = h
    int qt = blockIdx.y;   // 0..7, 128 q-rows each
    int b  = blockIdx.z;

    int tid = threadIdx.x;
    int w = tid >> 6, lane = tid & 63, lrow = lane & 15, quad = lane >> 4;

    __shared__ float bias_lds[1024];
    __shared__ __align__(16) _Float16 K_lds[2][32 * 64];  // [key][kd], col-blocks XOR'd by key&7
    __shared__ __align__(16) _Float16 V_s[2][256 * 32];   // [d][k-slot], PV-permuted key order

    for (int i = tid; i < 1024; i += 256) bias_lds[i] = biases[h * 1024 + i];

    // ---- Q fragments: frag f covers q-rows qt*128 + w*32 + f*16 + (0..15) ----
    int q0 = qt * 128 + w * 32 + lrow;
    const _Float16* qb = qk + ((size_t)(b * 1024 + q0)) * 1024 + h * 128;
    half8 aq[2][2];
    aq[0][0] = *(const half8*)(qb + quad * 8);
    aq[0][1] = *(const half8*)(qb + 32 + quad * 8);
    aq[1][0] = *(const half8*)(qb + 16 * 1024 + quad * 8);
    aq[1][1] = *(const half8*)(qb + 16 * 1024 + 32 + quad * 8);

    // ---- staging sources (per-lane global addresses; LDS dest is linear DMA) ----
    int kswz = (lane & 7) ^ ((lane >> 3) & 7);
    const _Float16* ksrc_g = qk + ((size_t)(b * 1024 + w * 8 + (lane >> 3))) * 1024 + h * 128 + 64 + kswz * 8;
    const _Float16* vsrc_g = vt + ((size_t)((b * 8 + h) * 256 + w * 64 + (lane >> 2))) * 1024 + (lane & 3) * 8;

    // ---- K read offsets (halves), loop-invariant: stored cb = (data cb) ^ (row&7)
    int koff0 = lrow * 64 + ((quad) ^ (lrow & 7)) * 8;
    int koff1 = lrow * 64 + ((4 + quad) ^ (lrow & 7)) * 8;

    int qr = qt * 4 + w;

    float m_[2] = {-1e30f, -1e30f}, l_[2] = {0.f, 0.f};
    floatx4 od[2][16];
#pragma unroll
    for (int f = 0; f < 2; ++f)
#pragma unroll
        for (int dt = 0; dt < 16; ++dt) od[f][dt] = (floatx4){0.f, 0.f, 0.f, 0.f};

#define STAGE(t)                                                                  \
    do {                                                                          \
        int bb_ = (t) & 1;                                                        \
        gload16(ksrc_g + (size_t)(t) * 32 * 1024, &K_lds[bb_][w * 8 * 64]);       \
        _Pragma("unroll") for (int it = 0; it < 4; ++it)                          \
            gload16(vsrc_g + (size_t)it * 16 * 1024 + (t) * 32,                   \
                    &V_s[bb_][(w * 64 + it * 16) * 32]);                          \
    } while (0)

    STAGE(0);
    __syncthreads();  // drains vmcnt -> tile 0 resident

    for (int kt = 0; kt < 32; ++kt) {
        int bufc = kt & 1;
        const _Float16* Kc = K_lds[bufc];
        const _Float16* Vc = V_s[bufc];

        // issue next tile's DMA into the other buffer (drained by end-of-iter barrier)
        if (kt < 31) STAGE(kt + 1);

        // ---- QK^T (swapped): sc[f][t][r] = S[q = lrow + f*16][key = t*16 + quad*4 + r]
        floatx4 sc[2][2];
#pragma unroll
        for (int f = 0; f < 2; ++f)
#pragma unroll
            for (int t = 0; t < 2; ++t) sc[f][t] = (floatx4){0.f, 0.f, 0.f, 0.f};
        {
            half8 ka = *(const half8*)&Kc[koff0];
            half8 kb = *(const half8*)&Kc[koff1];
            sc[0][0] = MFMA16(ka, aq[0][0], sc[0][0]);
            sc[0][0] = MFMA16(kb, aq[0][1], sc[0][0]);
            sc[1][0] = MFMA16(ka, aq[1][0], sc[1][0]);
            sc[1][0] = MFMA16(kb, aq[1][1], sc[1][0]);
            ka = *(const half8*)&Kc[16 * 64 + koff0];
            kb = *(const half8*)&Kc[16 * 64 + koff1];
            sc[0][1] = MFMA16(ka, aq[0][0], sc[0][1]);
            sc[0][1] = MFMA16(kb, aq[0][1], sc[0][1]);
            sc[1][1] = MFMA16(ka, aq[1][0], sc[1][1]);
            sc[1][1] = MFMA16(kb, aq[1][1], sc[1][1]);
        }

        int rowoff = abs(qr - kt) << 5;
        union H8 { _Float16 hh[8]; half8 v; } pa[2];

#pragma unroll
        for (int f = 0; f < 2; ++f) {
            int qcf = lrow + f * 16;
            float s_[8];
#pragma unroll
            for (int t = 0; t < 2; ++t)
#pragma unroll
                for (int r = 0; r < 4; ++r) {
                    int kc = t * 16 + quad * 4 + r;
                    s_[t * 4 + r] = sc[f][t][r] * 0.125f + bias_lds[rowoff + abs(qcf - kc)];
                }

            float pmax = fmaxf(fmaxf(fmaxf(s_[0], s_[1]), fmaxf(s_[2], s_[3])),
                               fmaxf(fmaxf(s_[4], s_[5]), fmaxf(s_[6], s_[7])));
            pmax = fmaxf(pmax, __shfl_xor(pmax, 16));
            pmax = fmaxf(pmax, __shfl_xor(pmax, 32));

            if (!__all(pmax - m_[f] <= 8.f)) {
                float mnew = fmaxf(m_[f], pmax);
                float alpha = __expf(m_[f] - mnew);
                m_[f] = mnew;
                l_[f] *= alpha;
                float a4[4];
#pragma unroll
                for (int r = 0; r < 4; ++r) a4[r] = __shfl(alpha, quad * 4 + r, 16);
#pragma unroll
                for (int dt = 0; dt < 16; ++dt)
#pragma unroll
                    for (int r = 0; r < 4; ++r) od[f][dt][r] *= a4[r];
            }

            float rs = 0.f;
#pragma unroll
            for (int i = 0; i < 8; ++i) {
                float p = __expf(s_[i] - m_[f]);
                pa[f].hh[i] = (_Float16)p;
                rs += p;
            }
            rs += __shfl_xor(rs, 16);
            rs += __shfl_xor(rs, 32);
            l_[f] += rs;
        }

        // ---- PV: one bv read feeds both fragments ----
#pragma unroll
        for (int dt = 0; dt < 16; ++dt) {
            half8 bv = *(const half8*)&Vc[(dt * 16 + lrow) * 32 + quad * 8];
            od[0][dt] = MFMA16(pa[0].v, bv, od[0][dt]);
            od[1][dt] = MFMA16(pa[1].v, bv, od[1][dt]);
        }
        __syncthreads();  // waves done with bufc; DMA for kt+1 drained
    }
#undef STAGE

#pragma unroll
    for (int f = 0; f < 2; ++f)
#pragma unroll
        for (int r = 0; r < 4; ++r) {
            float lq = __shfl(l_[f], quad * 4 + r, 16);
            float inv = 1.f / lq;
            int qg = qt * 128 + w * 32 + f * 16 + quad * 4 + r;
            _Float16* orow = out + ((size_t)(b * 1024 + qg)) * 2048 + h * 256;
#pragma unroll
            for (int dt = 0; dt < 16; ++dt)
                orow[dt * 16 + lrow] = (_Float16)(od[f][dt][r] * inv);
        }
}

// ---------------------------------------------------------------- launch
extern "C" void kernel_launch(void* const* d_in, const int* in_sizes, int n_in,
                              void* d_out, int out_size, void* d_ws, size_t ws_size,
                              hipStream_t stream) {
    const float* x      = (const float*)d_in[0];
    const float* gamma  = (const float*)d_in[1];
    const float* beta   = (const float*)d_in[2];
    const float* qkv_w  = (const float*)d_in[3];
    const float* qkv_b  = (const float*)d_in[4];
    const float* proj_w = (const float*)d_in[5];
    const float* proj_b = (const float*)d_in[6];
    const float* biases = (const float*)d_in[7];

    float* out = (float*)d_out;

    _Float16* ws      = (_Float16*)d_ws;
    _Float16* qkv_wt  = ws;                                   //  512*3072
    _Float16* proj_wt = qkv_wt + (size_t)512 * 3072;          // 2048*512
    _Float16* xn      = proj_wt + (size_t)2048 * 512;         // 32768*512
    _Float16* chunk0  = xn + (size_t)32768 * 512;

    const size_t FIXED_HALVES = (size_t)512 * 3072 + (size_t)2048 * 512 + (size_t)32768 * 512;
    int CB = 0;
    for (int cb : {16, 8, 4, 2, 1}) {
        size_t halves = FIXED_HALVES + (size_t)cb * 1024 * (1024 + 2048 + 2048);
        if (halves * sizeof(_Float16) <= ws_size) { CB = cb; break; }
    }
    if (CB == 0) return;
    _Float16* qk_c  = chunk0;                                 // CB*1024*1024
    _Float16* vt_c  = qk_c + (size_t)CB * 1024 * 1024;        // CB*1024*2048
    _Float16* att_c = vt_c + (size_t)CB * 1024 * 2048;        // CB*1024*2048

    transpose_cast<<<dim3(3072 / 32, 512 / 32), 256, 0, stream>>>(qkv_w, qkv_wt, 512, 3072);
    transpose_cast<<<dim3(512 / 32, 2048 / 32), 256, 0, stream>>>(proj_w, proj_wt, 2048, 512);
    ln_kernel<<<32768, 256, 0, stream>>>(x, gamma, beta, xn);

    const int MC = CB * 1024;
    for (int c = 0; c < 32 / CB; ++c) {
        const _Float16* xn_c = xn + (size_t)c * MC * 512;
        gemm_bt<2><<<dim3(MC / 128, 24), 256, 0, stream>>>(xn_c, qkv_wt, qkv_b,
                                                           (void*)qk_c, vt_c, MC, 3072, 512);
        attn_kernel<<<dim3(8, 8, CB), 256, 0, stream>>>(qk_c, vt_c, biases, att_c);
        float* out_c = out + (size_t)c * MC * 512;
        gemm_bt<1><<<dim3(MC / 128, 4), 256, 0, stream>>>(att_c, proj_wt, proj_b,
                                                          (void*)out_c, nullptr, MC, 512, 2048);
    }
}

// Round 9
// 804.571 us; speedup vs baseline: 1.5169x; 1.1269x over previous
//
#include <hip/hip_runtime.h>
#include <hip/hip_bf16.h>
#include <initializer_list>

typedef _Float16 half8 __attribute__((ext_vector_type(8)));
typedef float floatx4 __attribute__((ext_vector_type(4)));

#define MFMA16(a, b, c) __builtin_amdgcn_mfma_f32_16x16x32_f16((a), (b), (c), 0, 0, 0)

// async global->LDS, 16B per lane; LDS dest = wave-uniform base + lane*16
__device__ __forceinline__ void gload16(const void* g, void* l) {
    __builtin_amdgcn_global_load_lds((const __attribute__((address_space(1))) unsigned int*)g,
                                     (__attribute__((address_space(3))) unsigned int*)l,
                                     16, 0, 0);
}

// ---------------------------------------------------------------- LayerNorm
__global__ __launch_bounds__(256) void ln_kernel(const float* __restrict__ x,
                                                 const float* __restrict__ gamma,
                                                 const float* __restrict__ beta,
                                                 _Float16* __restrict__ xn) {
    int row = blockIdx.x;
    int tid = threadIdx.x;
    float2 v = ((const float2*)(x + (size_t)row * 512))[tid];

    __shared__ float red[4];
    __shared__ float mv[2];

    float s = v.x + v.y;
#pragma unroll
    for (int o = 32; o > 0; o >>= 1) s += __shfl_down(s, o);
    if ((tid & 63) == 0) red[tid >> 6] = s;
    __syncthreads();
    if (tid == 0) mv[0] = (red[0] + red[1] + red[2] + red[3]) * (1.f / 512.f);
    __syncthreads();
    float mean = mv[0];

    float dx = v.x - mean, dy = v.y - mean;
    float sq = dx * dx + dy * dy;
#pragma unroll
    for (int o = 32; o > 0; o >>= 1) sq += __shfl_xor(sq, o);
    __syncthreads();
    if ((tid & 63) == 0) red[tid >> 6] = sq;
    __syncthreads();
    if (tid == 0) mv[1] = rsqrtf((red[0] + red[1] + red[2] + red[3]) * (1.f / 512.f) + 1e-5f);
    __syncthreads();
    float rstd = mv[1];

    float g0 = gamma[tid * 2], g1 = gamma[tid * 2 + 1];
    float b0 = beta[tid * 2], b1 = beta[tid * 2 + 1];
    union { _Float16 h[2]; unsigned int u; } pk;
    pk.h[0] = (_Float16)(dx * rstd * g0 + b0);
    pk.h[1] = (_Float16)(dy * rstd * g1 + b1);
    ((unsigned int*)(xn + (size_t)row * 512))[tid] = pk.u;
}

// ------------------------------------------------- tiled transpose + cast fp32->fp16
__global__ __launch_bounds__(256) void transpose_cast(const float* __restrict__ in,
                                                      _Float16* __restrict__ out,
                                                      int R, int C) {
    __shared__ float t[32][33];
    int c0 = blockIdx.x * 32, r0 = blockIdx.y * 32;
    int tx = threadIdx.x & 31, ty = threadIdx.x >> 5;
#pragma unroll
    for (int j = 0; j < 4; ++j)
        t[ty + j * 8][tx] = in[(size_t)(r0 + ty + j * 8) * C + c0 + tx];
    __syncthreads();
#pragma unroll
    for (int j = 0; j < 4; ++j)
        out[(size_t)(c0 + ty + j * 8) * R + r0 + tx] = (_Float16)t[tx][ty + j * 8];
}

// ---------------------------------------------------------------- GEMM (B^T)
// OUTMODE 2's V writer stores vt in the PV-FRAGMENT-PERMUTED key order:
// within each 32-token tile, token kk = t*16 + q8*4 + r  ->  col q8*8 + t*4 + r.
template <int OUTMODE>
__global__ __launch_bounds__(256) void gemm_bt(const _Float16* __restrict__ A,
                                               const _Float16* __restrict__ Bt,
                                               const float* __restrict__ bias,
                                               void* __restrict__ Cout,
                                               _Float16* __restrict__ Vt,
                                               int M, int N, int K) {
    __shared__ __align__(16) _Float16 Asb[128 * 32];
    __shared__ __align__(16) _Float16 Bsb[128 * 32];

    int m0 = blockIdx.x * 128;
    int n0 = blockIdx.y * 128;
    int tid = threadIdx.x;
    int w = tid >> 6, lane = tid & 63, lrow = lane & 15, quad = lane >> 4;
    int wm = (w >> 1) * 64, wn = (w & 1) * 64;

    int hh = 0, part = 0;
    bool sw = false;
    if (OUTMODE == 2) {
        hh = blockIdx.y / 3;
        part = blockIdx.y - hh * 3;
        sw = (part != 0);
    }

    int srow = lane >> 2;
    int scb = (lane & 3) ^ ((lane >> 3) & 3);
    const _Float16* Abase = A + (size_t)(m0 + w * 16 + srow) * K + scb * 8;
    const _Float16* Bbase = Bt + (size_t)(n0 + w * 16 + srow) * K + scb * 8;
    char* AldsB = (char*)Asb + w * 1024;
    char* BldsB = (char*)Bsb + w * 1024;
    const size_t rowskip = (size_t)64 * K;

    int swz = (lrow >> 1) & 3;

    floatx4 acc[4][4];
#pragma unroll
    for (int i = 0; i < 4; ++i)
#pragma unroll
        for (int j = 0; j < 4; ++j) acc[i][j] = (floatx4){0.f, 0.f, 0.f, 0.f};

    for (int k0 = 0; k0 < K; k0 += 32) {
        __syncthreads();
        gload16(Abase + k0, AldsB);
        gload16(Abase + rowskip + k0, AldsB + 4096);
        gload16(Bbase + k0, BldsB);
        gload16(Bbase + rowskip + k0, BldsB + 4096);
        __syncthreads();

        half8 af[4], bf[4];
#pragma unroll
        for (int i = 0; i < 4; ++i) {
            int r = wm + i * 16 + lrow;
            af[i] = *(const half8*)&Asb[r * 32 + (quad ^ swz) * 8];
        }
#pragma unroll
        for (int j = 0; j < 4; ++j) {
            int r = wn + j * 16 + lrow;
            bf[j] = *(const half8*)&Bsb[r * 32 + (quad ^ swz) * 8];
        }
        if (OUTMODE == 2 && sw) {
#pragma unroll
            for (int i = 0; i < 4; ++i)
#pragma unroll
                for (int j = 0; j < 4; ++j)
                    acc[i][j] = MFMA16(bf[j], af[i], acc[i][j]);
        } else {
#pragma unroll
            for (int i = 0; i < 4; ++i)
#pragma unroll
                for (int j = 0; j < 4; ++j)
                    acc[i][j] = MFMA16(af[i], bf[j], acc[i][j]);
        }
    }

    if (OUTMODE == 2 && sw) {
        // transposed fragment: lane lrow <-> token, quad*4+r <-> d
        // token tok0 + i*16 + lrow stored PERMUTED: tile (i>>1), col (lrow>>2)*8 + (i&1)*4 + (lrow&3)
        int b_rel = m0 >> 10;
        int tok0 = (m0 & 1023) + wm;  // 64-aligned
        _Float16* vbase = Vt + (((size_t)b_rel * 8 + hh) * 256 + (part - 1) * 128) * 1024;
        int poff0 = ((lrow >> 2) << 3) + (lrow & 3);
#pragma unroll
        for (int j = 0; j < 4; ++j)
#pragma unroll
            for (int r = 0; r < 4; ++r) {
                int d = wn + j * 16 + quad * 4 + r;
                float bv = bias[n0 + d];
                _Float16* vrow = vbase + (size_t)d * 1024 + tok0;
#pragma unroll
                for (int i = 0; i < 4; ++i)
                    vrow[(i >> 1) * 32 + ((i & 1) << 2) + poff0] = (_Float16)(acc[i][j][r] + bv);
            }
        return;
    }

#pragma unroll
    for (int i = 0; i < 4; ++i)
#pragma unroll
        for (int j = 0; j < 4; ++j) {
            int colg = n0 + wn + j * 16 + lrow;
            int coll = wn + j * 16 + lrow;
            float bv = bias[colg];
#pragma unroll
            for (int r = 0; r < 4; ++r) {
                int rowg = m0 + wm + i * 16 + quad * 4 + r;
                float v = acc[i][j][r] + bv;
                if (OUTMODE == 1) {
                    ((float*)Cout)[(size_t)rowg * N + colg] = v;
                } else {
                    ((_Float16*)Cout)[(size_t)rowg * 1024 + hh * 128 + coll] = (_Float16)v;
                }
            }
        }
}

// ---------------------------------------------------------------- attention
// 1 q-fragment per wave (16 q-rows), 64 q/block, double-buffered K/V staged by
// global_load_lds. Low VGPR (od[16]=64) -> 4 waves/SIMD; LDS 44KB -> 3 blocks/CU
// -> ~12 waves/CU for latency hiding (round 8's 2-frag version was latency-bound
// at 8 waves/CU: nothing saturated, MfmaUtil 14/VALU 28/LDS ~35/HBM 6).
// K stored with source-pre-swizzled col-blocks (cb ^ (row&7)); V arrives from vt
// already in PV-fragment key order (permuted at the producer), staged linearly.
__global__ __launch_bounds__(256) void attn_kernel(const _Float16* __restrict__ qk,
                                                   const _Float16* __restrict__ vt,
                                                   const float* __restrict__ biases,
                                                   _Float16* __restrict__ out) {
    int h  = blockIdx.x;   // 0..7 -> XCD = h
    int qt = blockIdx.y;   // 0..15, 64 q-rows each
    int b  = blockIdx.z;

    int tid = threadIdx.x;
    int w = tid >> 6, lane = tid & 63, lrow = lane & 15, quad = lane >> 4;

    __shared__ float bias_lds[1024];
    __shared__ __align__(16) _Float16 K_lds[2][32 * 64];  // [key][kd], col-blocks XOR'd by key&7
    __shared__ __align__(16) _Float16 V_s[2][256 * 32];   // [d][k-slot], PV-permuted key order

    for (int i = tid; i < 1024; i += 256) bias_lds[i] = biases[h * 1024 + i];

    // ---- Q fragment: wave w covers q-rows qt*64 + w*16 + (0..15) ----
    int q0 = qt * 64 + w * 16 + lrow;
    const _Float16* qb = qk + ((size_t)(b * 1024 + q0)) * 1024 + h * 128;
    half8 aq0 = *(const half8*)(qb + quad * 8);
    half8 aq1 = *(const half8*)(qb + 32 + quad * 8);

    // ---- staging sources (per-lane global addresses; LDS dest is linear DMA) ----
    int kswz = (lane & 7) ^ ((lane >> 3) & 7);
    const _Float16* ksrc_g = qk + ((size_t)(b * 1024 + w * 8 + (lane >> 3))) * 1024 + h * 128 + 64 + kswz * 8;
    const _Float16* vsrc_g = vt + ((size_t)((b * 8 + h) * 256 + w * 64 + (lane >> 2))) * 1024 + (lane & 3) * 8;

    // ---- K read offsets (halves), loop-invariant: stored cb = (data cb) ^ (row&7)
    int koff0 = lrow * 64 + ((quad) ^ (lrow & 7)) * 8;
    int koff1 = lrow * 64 + ((4 + quad) ^ (lrow & 7)) * 8;

    // bias row/col: q0 = qt*64 + w*16 + lrow -> qr independent of lrow
    int qr = qt * 2 + (w >> 1);
    int qcf = (w & 1) * 16 + lrow;

    float m_ = -1e30f, l_ = 0.f;
    floatx4 od[16];
#pragma unroll
    for (int dt = 0; dt < 16; ++dt) od[dt] = (floatx4){0.f, 0.f, 0.f, 0.f};

#define STAGE(t)                                                                  \
    do {                                                                          \
        int bb_ = (t) & 1;                                                        \
        gload16(ksrc_g + (size_t)(t) * 32 * 1024, &K_lds[bb_][w * 8 * 64]);       \
        _Pragma("unroll") for (int it = 0; it < 4; ++it)                          \
            gload16(vsrc_g + (size_t)it * 16 * 1024 + (t) * 32,                   \
                    &V_s[bb_][(w * 64 + it * 16) * 32]);                          \
    } while (0)

    STAGE(0);
    __syncthreads();  // drains vmcnt -> tile 0 resident

    for (int kt = 0; kt < 32; ++kt) {
        int bufc = kt & 1;
        const _Float16* Kc = K_lds[bufc];
        const _Float16* Vc = V_s[bufc];

        // issue next tile's DMA into the other buffer (drained by end-of-iter barrier)
        if (kt < 31) STAGE(kt + 1);

        // ---- QK^T (swapped): sc[t][r] = S[q = lrow][key = t*16 + quad*4 + r]
        floatx4 sc0 = (floatx4){0.f, 0.f, 0.f, 0.f}, sc1 = sc0;
        {
            half8 ka = *(const half8*)&Kc[koff0];
            half8 kb = *(const half8*)&Kc[koff1];
            sc0 = MFMA16(ka, aq0, sc0);
            sc0 = MFMA16(kb, aq1, sc0);
            ka = *(const half8*)&Kc[16 * 64 + koff0];
            kb = *(const half8*)&Kc[16 * 64 + koff1];
            sc1 = MFMA16(ka, aq0, sc1);
            sc1 = MFMA16(kb, aq1, sc1);
        }

        int rowoff = abs(qr - kt) << 5;
        float s_[8];
#pragma unroll
        for (int r = 0; r < 4; ++r) {
            int kc0 = quad * 4 + r;
            s_[r] = sc0[r] * 0.125f + bias_lds[rowoff + abs(qcf - kc0)];
            s_[4 + r] = sc1[r] * 0.125f + bias_lds[rowoff + abs(qcf - (16 + kc0))];
        }

        float pmax = fmaxf(fmaxf(fmaxf(s_[0], s_[1]), fmaxf(s_[2], s_[3])),
                           fmaxf(fmaxf(s_[4], s_[5]), fmaxf(s_[6], s_[7])));
        pmax = fmaxf(pmax, __shfl_xor(pmax, 16));
        pmax = fmaxf(pmax, __shfl_xor(pmax, 32));

        if (!__all(pmax - m_ <= 8.f)) {
            float mnew = fmaxf(m_, pmax);
            float alpha = __expf(m_ - mnew);
            m_ = mnew;
            l_ *= alpha;
            float a4[4];
#pragma unroll
            for (int r = 0; r < 4; ++r) a4[r] = __shfl(alpha, quad * 4 + r, 16);
#pragma unroll
            for (int dt = 0; dt < 16; ++dt)
#pragma unroll
                for (int r = 0; r < 4; ++r) od[dt][r] *= a4[r];
        }

        union H8 { _Float16 hh[8]; half8 v; } pa;
        float rs = 0.f;
#pragma unroll
        for (int i = 0; i < 8; ++i) {
            float p = __expf(s_[i] - m_);
            pa.hh[i] = (_Float16)p;
            rs += p;
        }
        rs += __shfl_xor(rs, 16);
        rs += __shfl_xor(rs, 32);
        l_ += rs;

        // ---- PV: pa slot j = quad*8 + t*4 + r <-> key t*16 + quad*4 + r (vt pre-permuted)
#pragma unroll
        for (int dt = 0; dt < 16; ++dt) {
            half8 bv = *(const half8*)&Vc[(dt * 16 + lrow) * 32 + quad * 8];
            od[dt] = MFMA16(pa.v, bv, od[dt]);
        }
        __syncthreads();  // waves done with bufc; DMA for kt+1 drained
    }
#undef STAGE

#pragma unroll
    for (int r = 0; r < 4; ++r) {
        float lq = __shfl(l_, quad * 4 + r, 16);
        float inv = 1.f / lq;
        int qg = qt * 64 + w * 16 + quad * 4 + r;
        _Float16* orow = out + ((size_t)(b * 1024 + qg)) * 2048 + h * 256;
#pragma unroll
        for (int dt = 0; dt < 16; ++dt)
            orow[dt * 16 + lrow] = (_Float16)(od[dt][r] * inv);
    }
}

// ---------------------------------------------------------------- launch
extern "C" void kernel_launch(void* const* d_in, const int* in_sizes, int n_in,
                              void* d_out, int out_size, void* d_ws, size_t ws_size,
                              hipStream_t stream) {
    const float* x      = (const float*)d_in[0];
    const float* gamma  = (const float*)d_in[1];
    const float* beta   = (const float*)d_in[2];
    const float* qkv_w  = (const float*)d_in[3];
    const float* qkv_b  = (const float*)d_in[4];
    const float* proj_w = (const float*)d_in[5];
    const float* proj_b = (const float*)d_in[6];
    const float* biases = (const float*)d_in[7];

    float* out = (float*)d_out;

    _Float16* ws      = (_Float16*)d_ws;
    _Float16* qkv_wt  = ws;                                   //  512*3072
    _Float16* proj_wt = qkv_wt + (size_t)512 * 3072;          // 2048*512
    _Float16* xn      = proj_wt + (size_t)2048 * 512;         // 32768*512
    _Float16* chunk0  = xn + (size_t)32768 * 512;

    const size_t FIXED_HALVES = (size_t)512 * 3072 + (size_t)2048 * 512 + (size_t)32768 * 512;
    int CB = 0;
    for (int cb : {16, 8, 4, 2, 1}) {
        size_t halves = FIXED_HALVES + (size_t)cb * 1024 * (1024 + 2048 + 2048);
        if (halves * sizeof(_Float16) <= ws_size) { CB = cb; break; }
    }
    if (CB == 0) return;
    _Float16* qk_c  = chunk0;                                 // CB*1024*1024
    _Float16* vt_c  = qk_c + (size_t)CB * 1024 * 1024;        // CB*1024*2048
    _Float16* att_c = vt_c + (size_t)CB * 1024 * 2048;        // CB*1024*2048

    transpose_cast<<<dim3(3072 / 32, 512 / 32), 256, 0, stream>>>(qkv_w, qkv_wt, 512, 3072);
    transpose_cast<<<dim3(512 / 32, 2048 / 32), 256, 0, stream>>>(proj_w, proj_wt, 2048, 512);
    ln_kernel<<<32768, 256, 0, stream>>>(x, gamma, beta, xn);

    const int MC = CB * 1024;
    for (int c = 0; c < 32 / CB; ++c) {
        const _Float16* xn_c = xn + (size_t)c * MC * 512;
        gemm_bt<2><<<dim3(MC / 128, 24), 256, 0, stream>>>(xn_c, qkv_wt, qkv_b,
                                                           (void*)qk_c, vt_c, MC, 3072, 512);
        attn_kernel<<<dim3(8, 16, CB), 256, 0, stream>>>(qk_c, vt_c, biases, att_c);
        float* out_c = out + (size_t)c * MC * 512;
        gemm_bt<1><<<dim3(MC / 128, 4), 256, 0, stream>>>(att_c, proj_wt, proj_b,
                                                          (void*)out_c, nullptr, MC, 512, 2048);
    }
}

// Round 10
// 715.844 us; speedup vs baseline: 1.7049x; 1.1239x over previous
//
#include <hip/hip_runtime.h>
#include <hip/hip_bf16.h>
#include <initializer_list>

typedef _Float16 half8 __attribute__((ext_vector_type(8)));
typedef float floatx4 __attribute__((ext_vector_type(4)));

#define MFMA16(a, b, c) __builtin_amdgcn_mfma_f32_16x16x32_f16((a), (b), (c), 0, 0, 0)

// async global->LDS, 16B per lane; LDS dest = wave-uniform base + lane*16
__device__ __forceinline__ void gload16(const void* g, void* l) {
    __builtin_amdgcn_global_load_lds((const __attribute__((address_space(1))) unsigned int*)g,
                                     (__attribute__((address_space(3))) unsigned int*)l,
                                     16, 0, 0);
}

// ---------------------------------------------------------------- LayerNorm
__global__ __launch_bounds__(256) void ln_kernel(const float* __restrict__ x,
                                                 const float* __restrict__ gamma,
                                                 const float* __restrict__ beta,
                                                 _Float16* __restrict__ xn) {
    int row = blockIdx.x;
    int tid = threadIdx.x;
    float2 v = ((const float2*)(x + (size_t)row * 512))[tid];

    __shared__ float red[4];
    __shared__ float mv[2];

    float s = v.x + v.y;
#pragma unroll
    for (int o = 32; o > 0; o >>= 1) s += __shfl_down(s, o);
    if ((tid & 63) == 0) red[tid >> 6] = s;
    __syncthreads();
    if (tid == 0) mv[0] = (red[0] + red[1] + red[2] + red[3]) * (1.f / 512.f);
    __syncthreads();
    float mean = mv[0];

    float dx = v.x - mean, dy = v.y - mean;
    float sq = dx * dx + dy * dy;
#pragma unroll
    for (int o = 32; o > 0; o >>= 1) sq += __shfl_xor(sq, o);
    __syncthreads();
    if ((tid & 63) == 0) red[tid >> 6] = sq;
    __syncthreads();
    if (tid == 0) mv[1] = rsqrtf((red[0] + red[1] + red[2] + red[3]) * (1.f / 512.f) + 1e-5f);
    __syncthreads();
    float rstd = mv[1];

    float g0 = gamma[tid * 2], g1 = gamma[tid * 2 + 1];
    float b0 = beta[tid * 2], b1 = beta[tid * 2 + 1];
    union { _Float16 h[2]; unsigned int u; } pk;
    pk.h[0] = (_Float16)(dx * rstd * g0 + b0);
    pk.h[1] = (_Float16)(dy * rstd * g1 + b1);
    ((unsigned int*)(xn + (size_t)row * 512))[tid] = pk.u;
}

// ------------------------------------------------- tiled transpose + cast fp32->fp16
__global__ __launch_bounds__(256) void transpose_cast(const float* __restrict__ in,
                                                      _Float16* __restrict__ out,
                                                      int R, int C) {
    __shared__ float t[32][33];
    int c0 = blockIdx.x * 32, r0 = blockIdx.y * 32;
    int tx = threadIdx.x & 31, ty = threadIdx.x >> 5;
#pragma unroll
    for (int j = 0; j < 4; ++j)
        t[ty + j * 8][tx] = in[(size_t)(r0 + ty + j * 8) * C + c0 + tx];
    __syncthreads();
#pragma unroll
    for (int j = 0; j < 4; ++j)
        out[(size_t)(c0 + ty + j * 8) * R + r0 + tx] = (_Float16)t[tx][ty + j * 8];
}

// ---------------------------------------------------------------- GEMM (B^T)
// OUTMODE 2's V writer stores vt in the PV-FRAGMENT-PERMUTED key order:
// within each 32-token tile, token kk = t*16 + q8*4 + r  ->  col q8*8 + t*4 + r.
template <int OUTMODE>
__global__ __launch_bounds__(256) void gemm_bt(const _Float16* __restrict__ A,
                                               const _Float16* __restrict__ Bt,
                                               const float* __restrict__ bias,
                                               void* __restrict__ Cout,
                                               _Float16* __restrict__ Vt,
                                               int M, int N, int K) {
    __shared__ __align__(16) _Float16 Asb[128 * 32];
    __shared__ __align__(16) _Float16 Bsb[128 * 32];

    int m0 = blockIdx.x * 128;
    int n0 = blockIdx.y * 128;
    int tid = threadIdx.x;
    int w = tid >> 6, lane = tid & 63, lrow = lane & 15, quad = lane >> 4;
    int wm = (w >> 1) * 64, wn = (w & 1) * 64;

    int hh = 0, part = 0;
    bool sw = false;
    if (OUTMODE == 2) {
        hh = blockIdx.y / 3;
        part = blockIdx.y - hh * 3;
        sw = (part != 0);
    }

    int srow = lane >> 2;
    int scb = (lane & 3) ^ ((lane >> 3) & 3);
    const _Float16* Abase = A + (size_t)(m0 + w * 16 + srow) * K + scb * 8;
    const _Float16* Bbase = Bt + (size_t)(n0 + w * 16 + srow) * K + scb * 8;
    char* AldsB = (char*)Asb + w * 1024;
    char* BldsB = (char*)Bsb + w * 1024;
    const size_t rowskip = (size_t)64 * K;

    int swz = (lrow >> 1) & 3;

    floatx4 acc[4][4];
#pragma unroll
    for (int i = 0; i < 4; ++i)
#pragma unroll
        for (int j = 0; j < 4; ++j) acc[i][j] = (floatx4){0.f, 0.f, 0.f, 0.f};

    for (int k0 = 0; k0 < K; k0 += 32) {
        __syncthreads();
        gload16(Abase + k0, AldsB);
        gload16(Abase + rowskip + k0, AldsB + 4096);
        gload16(Bbase + k0, BldsB);
        gload16(Bbase + rowskip + k0, BldsB + 4096);
        __syncthreads();

        half8 af[4], bf[4];
#pragma unroll
        for (int i = 0; i < 4; ++i) {
            int r = wm + i * 16 + lrow;
            af[i] = *(const half8*)&Asb[r * 32 + (quad ^ swz) * 8];
        }
#pragma unroll
        for (int j = 0; j < 4; ++j) {
            int r = wn + j * 16 + lrow;
            bf[j] = *(const half8*)&Bsb[r * 32 + (quad ^ swz) * 8];
        }
        if (OUTMODE == 2 && sw) {
#pragma unroll
            for (int i = 0; i < 4; ++i)
#pragma unroll
                for (int j = 0; j < 4; ++j)
                    acc[i][j] = MFMA16(bf[j], af[i], acc[i][j]);
        } else {
#pragma unroll
            for (int i = 0; i < 4; ++i)
#pragma unroll
                for (int j = 0; j < 4; ++j)
                    acc[i][j] = MFMA16(af[i], bf[j], acc[i][j]);
        }
    }

    if (OUTMODE == 2 && sw) {
        // transposed fragment: lane lrow <-> token, quad*4+r <-> d
        // token tok0 + i*16 + lrow stored PERMUTED: tile (i>>1), col (lrow>>2)*8 + (i&1)*4 + (lrow&3)
        int b_rel = m0 >> 10;
        int tok0 = (m0 & 1023) + wm;  // 64-aligned
        _Float16* vbase = Vt + (((size_t)b_rel * 8 + hh) * 256 + (part - 1) * 128) * 1024;
        int poff0 = ((lrow >> 2) << 3) + (lrow & 3);
#pragma unroll
        for (int j = 0; j < 4; ++j)
#pragma unroll
            for (int r = 0; r < 4; ++r) {
                int d = wn + j * 16 + quad * 4 + r;
                float bv = bias[n0 + d];
                _Float16* vrow = vbase + (size_t)d * 1024 + tok0;
#pragma unroll
                for (int i = 0; i < 4; ++i)
                    vrow[(i >> 1) * 32 + ((i & 1) << 2) + poff0] = (_Float16)(acc[i][j][r] + bv);
            }
        return;
    }

#pragma unroll
    for (int i = 0; i < 4; ++i)
#pragma unroll
        for (int j = 0; j < 4; ++j) {
            int colg = n0 + wn + j * 16 + lrow;
            int coll = wn + j * 16 + lrow;
            float bv = bias[colg];
#pragma unroll
            for (int r = 0; r < 4; ++r) {
                int rowg = m0 + wm + i * 16 + quad * 4 + r;
                float v = acc[i][j][r] + bv;
                if (OUTMODE == 1) {
                    ((float*)Cout)[(size_t)rowg * N + colg] = v;
                } else {
                    ((_Float16*)Cout)[(size_t)rowg * 1024 + hh * 128 + coll] = (_Float16)v;
                }
            }
        }
}

// ---------------------------------------------------------------- attention
// 512 threads = 8 waves, 1 q-fragment (16 q-rows) per wave -> 128 q/block.
// K/V DMA traffic per q-row HALVED vs 256-thread version; VGPR ~104 ->
// 4 waves/SIMD -> 2 blocks/CU = 16 waves/CU.
// Bias as RELATIVE table rel[dr][qc-kc+31] (32x64 f32): gather addresses are
// consecutive ints per instruction -> conflict-free (the abs() fold was the
// source of the 1.7e7 bank conflicts in round 9).
__global__ __launch_bounds__(512) void attn_kernel(const _Float16* __restrict__ qk,
                                                   const _Float16* __restrict__ vt,
                                                   const float* __restrict__ biases,
                                                   _Float16* __restrict__ out) {
    int h  = blockIdx.x;   // 0..7 -> XCD = h
    int qt = blockIdx.y;   // 0..7, 128 q-rows each
    int b  = blockIdx.z;

    int tid = threadIdx.x;
    int w = tid >> 6, lane = tid & 63, lrow = lane & 15, quad = lane >> 4;

    __shared__ float rel[32 * 64];                        // bias rel table, 8 KB
    __shared__ __align__(16) _Float16 K_lds[2][32 * 64];  // [key][kd], col-blocks XOR'd by key&7
    __shared__ __align__(16) _Float16 V_s[2][256 * 32];   // [d][k-slot], PV-permuted key order

    // build relative-bias table: rel[dr][c] = bias[h][dr*32 + |c-31|]
    for (int i = tid; i < 2048; i += 512) {
        int dr = i >> 6, c = i & 63;
        int d = c - 31;
        int a = d < 0 ? -d : d;
        if (a > 31) a = 31;  // c==63 never read
        rel[i] = biases[h * 1024 + dr * 32 + a];
    }

    // ---- Q fragment: wave w covers q-rows qt*128 + w*16 + (0..15) ----
    int q0 = qt * 128 + w * 16 + lrow;
    const _Float16* qb = qk + ((size_t)(b * 1024 + q0)) * 1024 + h * 128;
    half8 aq0 = *(const half8*)(qb + quad * 8);
    half8 aq1 = *(const half8*)(qb + 32 + quad * 8);

    // ---- staging sources (per-lane global addresses; LDS dest is linear DMA) ----
    int kswz = (lane & 7) ^ ((lane >> 3) & 7);
    const _Float16* ksrc_g = qk + ((size_t)(b * 1024 + (w & 3) * 8 + (lane >> 3))) * 1024 + h * 128 + 64 + kswz * 8;
    const _Float16* vsrc_g = vt + ((size_t)((b * 8 + h) * 256 + w * 32 + (lane >> 2))) * 1024 + (lane & 3) * 8;

    // ---- K read offsets (halves), loop-invariant: stored cb = (data cb) ^ (row&7)
    int koff0 = lrow * 64 + ((quad) ^ (lrow & 7)) * 8;
    int koff1 = lrow * 64 + ((4 + quad) ^ (lrow & 7)) * 8;

    // bias: q0 = qt*128 + w*16 + lrow -> qr = qt*4 + (w>>1), qc = (w&1)*16 + lrow
    int qr = qt * 4 + (w >> 1);
    int qcf = (w & 1) * 16 + lrow;
    int bbase0 = qcf - quad * 4 + 28;  // addr_r = bbase0 + (3-r); >=16
    // second half: bbase0 - 16; min addr 0

    float m_ = -1e30f, l_ = 0.f;
    floatx4 od[16];
#pragma unroll
    for (int dt = 0; dt < 16; ++dt) od[dt] = (floatx4){0.f, 0.f, 0.f, 0.f};

#define STAGE(t)                                                                  \
    do {                                                                          \
        int bb_ = (t) & 1;                                                        \
        if (w < 4) gload16(ksrc_g + (size_t)(t) * 32 * 1024, &K_lds[bb_][w * 8 * 64]); \
        gload16(vsrc_g + (size_t)(t) * 32, &V_s[bb_][(w * 32) * 32]);             \
        gload16(vsrc_g + (size_t)16 * 1024 + (size_t)(t) * 32,                    \
                &V_s[bb_][(w * 32 + 16) * 32]);                                   \
    } while (0)

    STAGE(0);
    __syncthreads();  // drains vmcnt -> tile 0 resident; rel table visible

    for (int kt = 0; kt < 32; ++kt) {
        int bufc = kt & 1;
        const _Float16* Kc = K_lds[bufc];
        const _Float16* Vc = V_s[bufc];

        // issue next tile's DMA into the other buffer (drained by end-of-iter barrier)
        if (kt < 31) STAGE(kt + 1);

        // ---- QK^T (swapped): sc[t][r] = S[q = lrow][key = t*16 + quad*4 + r]
        floatx4 sc0 = (floatx4){0.f, 0.f, 0.f, 0.f}, sc1 = sc0;
        {
            half8 ka = *(const half8*)&Kc[koff0];
            half8 kb = *(const half8*)&Kc[koff1];
            sc0 = MFMA16(ka, aq0, sc0);
            sc0 = MFMA16(kb, aq1, sc0);
            ka = *(const half8*)&Kc[16 * 64 + koff0];
            kb = *(const half8*)&Kc[16 * 64 + koff1];
            sc1 = MFMA16(ka, aq0, sc1);
            sc1 = MFMA16(kb, aq1, sc1);
        }

        int dr = qr - kt; if (dr < 0) dr = -dr;
        int rb0 = dr * 64 + bbase0;
        float s_[8];
#pragma unroll
        for (int r = 0; r < 4; ++r) {
            s_[r] = sc0[r] * 0.125f + rel[rb0 + (3 - r)];
            s_[4 + r] = sc1[r] * 0.125f + rel[rb0 - 16 + (3 - r)];
        }

        float pmax = fmaxf(fmaxf(fmaxf(s_[0], s_[1]), fmaxf(s_[2], s_[3])),
                           fmaxf(fmaxf(s_[4], s_[5]), fmaxf(s_[6], s_[7])));
        pmax = fmaxf(pmax, __shfl_xor(pmax, 16));
        pmax = fmaxf(pmax, __shfl_xor(pmax, 32));

        if (!__all(pmax - m_ <= 8.f)) {
            float mnew = fmaxf(m_, pmax);
            float alpha = __expf(m_ - mnew);
            m_ = mnew;
            l_ *= alpha;
            float a4[4];
#pragma unroll
            for (int r = 0; r < 4; ++r) a4[r] = __shfl(alpha, quad * 4 + r, 16);
#pragma unroll
            for (int dt = 0; dt < 16; ++dt)
#pragma unroll
                for (int r = 0; r < 4; ++r) od[dt][r] *= a4[r];
        }

        union H8 { _Float16 hh[8]; half8 v; } pa;
        float rs = 0.f;
#pragma unroll
        for (int i = 0; i < 8; ++i) {
            float p = __expf(s_[i] - m_);
            pa.hh[i] = (_Float16)p;
            rs += p;
        }
        rs += __shfl_xor(rs, 16);
        rs += __shfl_xor(rs, 32);
        l_ += rs;

        // ---- PV: pa slot j = quad*8 + t*4 + r <-> key t*16 + quad*4 + r (vt pre-permuted)
#pragma unroll
        for (int dt = 0; dt < 16; ++dt) {
            half8 bv = *(const half8*)&Vc[(dt * 16 + lrow) * 32 + quad * 8];
            od[dt] = MFMA16(pa.v, bv, od[dt]);
        }
        __syncthreads();  // waves done with bufc; DMA for kt+1 drained
    }
#undef STAGE

#pragma unroll
    for (int r = 0; r < 4; ++r) {
        float lq = __shfl(l_, quad * 4 + r, 16);
        float inv = 1.f / lq;
        int qg = qt * 128 + w * 16 + quad * 4 + r;
        _Float16* orow = out + ((size_t)(b * 1024 + qg)) * 2048 + h * 256;
#pragma unroll
        for (int dt = 0; dt < 16; ++dt)
            orow[dt * 16 + lrow] = (_Float16)(od[dt][r] * inv);
    }
}

// ---------------------------------------------------------------- launch
extern "C" void kernel_launch(void* const* d_in, const int* in_sizes, int n_in,
                              void* d_out, int out_size, void* d_ws, size_t ws_size,
                              hipStream_t stream) {
    const float* x      = (const float*)d_in[0];
    const float* gamma  = (const float*)d_in[1];
    const float* beta   = (const float*)d_in[2];
    const float* qkv_w  = (const float*)d_in[3];
    const float* qkv_b  = (const float*)d_in[4];
    const float* proj_w = (const float*)d_in[5];
    const float* proj_b = (const float*)d_in[6];
    const float* biases = (const float*)d_in[7];

    float* out = (float*)d_out;

    _Float16* ws      = (_Float16*)d_ws;
    _Float16* qkv_wt  = ws;                                   //  512*3072
    _Float16* proj_wt = qkv_wt + (size_t)512 * 3072;          // 2048*512
    _Float16* xn      = proj_wt + (size_t)2048 * 512;         // 32768*512
    _Float16* chunk0  = xn + (size_t)32768 * 512;

    const size_t FIXED_HALVES = (size_t)512 * 3072 + (size_t)2048 * 512 + (size_t)32768 * 512;
    int CB = 0;
    for (int cb : {16, 8, 4, 2, 1}) {
        size_t halves = FIXED_HALVES + (size_t)cb * 1024 * (1024 + 2048 + 2048);
        if (halves * sizeof(_Float16) <= ws_size) { CB = cb; break; }
    }
    if (CB == 0) return;
    _Float16* qk_c  = chunk0;                                 // CB*1024*1024
    _Float16* vt_c  = qk_c + (size_t)CB * 1024 * 1024;        // CB*1024*2048
    _Float16* att_c = vt_c + (size_t)CB * 1024 * 2048;        // CB*1024*2048

    transpose_cast<<<dim3(3072 / 32, 512 / 32), 256, 0, stream>>>(qkv_w, qkv_wt, 512, 3072);
    transpose_cast<<<dim3(512 / 32, 2048 / 32), 256, 0, stream>>>(proj_w, proj_wt, 2048, 512);
    ln_kernel<<<32768, 256, 0, stream>>>(x, gamma, beta, xn);

    const int MC = CB * 1024;
    for (int c = 0; c < 32 / CB; ++c) {
        const _Float16* xn_c = xn + (size_t)c * MC * 512;
        gemm_bt<2><<<dim3(MC / 128, 24), 256, 0, stream>>>(xn_c, qkv_wt, qkv_b,
                                                           (void*)qk_c, vt_c, MC, 3072, 512);
        attn_kernel<<<dim3(8, 8, CB), 512, 0, stream>>>(qk_c, vt_c, biases, att_c);
        float* out_c = out + (size_t)c * MC * 512;
        gemm_bt<1><<<dim3(MC / 128, 4), 256, 0, stream>>>(att_c, proj_wt, proj_b,
                                                          (void*)out_c, nullptr, MC, 512, 2048);
    }
}